// Round 11
// baseline (145.920 us; speedup 1.0000x reference)
//
#include <hip/hip_runtime.h>
#include <hip/hip_bf16.h>
#include <math.h>

#define BB 2
#define SS 2048
#define HH 16
#define DH 64
#define DQK 128
#define DD (HH*DH)
// Q folded scale = (1/sqrt(128)) * log2(e)  -> scores arrive in log2 domain
#define QS2   0.12751758f
// 8 * log2(e): fixed-max bias in log2 domain (cancels exactly in softmax)
#define EBIAS 11.5415605f

typedef _Float16 half8_t __attribute__((ext_vector_type(8)));
typedef _Float16 half4_t __attribute__((ext_vector_type(4)));
typedef float f32x4_t __attribute__((ext_vector_type(4)));
typedef float f32x4v __attribute__((ext_vector_type(4)));

// Direct hardware trig on REVOLUTIONS (v_sin_f32: D=sin(S0*2pi)).
__device__ __forceinline__ void fsincos(float th, float* sn, float* cs) {
  float rev = th * 0.15915494309189535f;
  rev -= floorf(rev);
  *sn = __builtin_amdgcn_sinf(rev);
  *cs = __builtin_amdgcn_cosf(rev);
}
// cos(th)+sin(th) = sqrt(2)*sin(th + pi/4): ONE transcendental.
__device__ __forceinline__ float fsc_sum(float th) {
  float rev = th * 0.15915494309189535f + 0.125f;
  rev -= floorf(rev);
  return 1.41421356237f * __builtin_amdgcn_sinf(rev);
}

// async global->LDS DMA, 16B/lane, LDS dest = uniform base + lane*16
__device__ __forceinline__ void dma16(const void* g, void* l) {
  __builtin_amdgcn_global_load_lds(
      (const __attribute__((address_space(1))) unsigned int*)g,
      (__attribute__((address_space(3))) unsigned int*)l, 16, 0, 0);
}

// Block per (bh, s-tile of 64). Emits:
//   Q  row-major [bh][s][128], scale QS2 folded (log2-domain scores)
//   K  swizzled  [bh][ktile64][d8 0..15][key 0..63] 16B units
//   V  swizzled  [bh][ktile64][k8 0..7][dv 0..63]  16B units
__global__ __launch_bounds__(256) void gen_qkv(
    const float* __restrict__ x,
    const float* __restrict__ wq, const float* __restrict__ bq,
    const float* __restrict__ phq,
    const float* __restrict__ wk, const float* __restrict__ bk,
    const float* __restrict__ phk,
    const float* __restrict__ wv, const float* __restrict__ bv,
    _Float16* __restrict__ Qd, _Float16* __restrict__ Kd, _Float16* __restrict__ Vtd)
{
  int stile = blockIdx.x & 31;
  int bh    = blockIdx.x >> 5;
  int b = bh >> 4, h = bh & 15;
  int t = threadIdx.x;
  int sl = t >> 2;                 // 0..63 (key/row within tile)
  int dq = (t & 3) << 4;           // 0,16,32,48
  int s  = stile * 64 + sl;

  __shared__ _Float16 Vl[64 * 65]; // transpose buffer, odd pitch

  const float* xr = x + (((size_t)b * SS + s) * HH + h) * DH + dq;
  float xv[16];
#pragma unroll
  for (int i = 0; i < 4; i++)
    *(f32x4v*)(&xv[i * 4]) = *(const f32x4v*)(xr + i * 4);

  int hd0 = h * DH + dq;
  float iwqv[16], vbq[16], vpq[16];
  float iwkv[16], vbk[16], vpk[16];
  float iwvv[16], vbv[16];
#pragma unroll
  for (int i = 0; i < 4; i++) {
    f32x4v w4, b4, p4;
    w4 = *(const f32x4v*)(wq + hd0 + i * 4);
    b4 = *(const f32x4v*)(bq + hd0 + i * 4);
    p4 = *(const f32x4v*)(phq + hd0 + i * 4);
#pragma unroll
    for (int j = 0; j < 4; j++) {
      iwqv[i*4+j] = __builtin_amdgcn_rcpf(1.f + fabsf(w4[j]));
      vbq[i*4+j] = b4[j]; vpq[i*4+j] = p4[j];
    }
    w4 = *(const f32x4v*)(wk + hd0 + i * 4);
    b4 = *(const f32x4v*)(bk + hd0 + i * 4);
    p4 = *(const f32x4v*)(phk + hd0 + i * 4);
#pragma unroll
    for (int j = 0; j < 4; j++) {
      iwkv[i*4+j] = __builtin_amdgcn_rcpf(1.f + fabsf(w4[j]));
      vbk[i*4+j] = b4[j]; vpk[i*4+j] = p4[j];
    }
    w4 = *(const f32x4v*)(wv + hd0 + i * 4);
    b4 = *(const f32x4v*)(bv + hd0 + i * 4);
#pragma unroll
    for (int j = 0; j < 4; j++) {
      iwvv[i*4+j] = __builtin_amdgcn_rcpf(1.f + fabsf(w4[j]));
      vbv[i*4+j] = b4[j];
    }
  }

  float tv = (float)s;
  _Float16 qc[16], qs[16], kc[16], ks[16];
#pragma unroll
  for (int i = 0; i < 16; i++) {
    int d = dq + i;
    {
      float th = xv[i] * iwqv[i] + vbq[i] + tv * vpq[i];
      float sn, cs; fsincos(th, &sn, &cs);
      qc[i] = (_Float16)(cs * QS2);
      qs[i] = (_Float16)(sn * QS2);
    }
    {
      float th = xv[i] * iwkv[i] + vbk[i] + tv * vpk[i];
      float sn, cs; fsincos(th, &sn, &cs);
      kc[i] = (_Float16)cs;
      ks[i] = (_Float16)sn;
    }
    {
      float th = xv[i] * iwvv[i] + vbv[i];
      Vl[d * 65 + sl] = (_Float16)fsc_sum(th);
    }
  }
  // Q row-major
  size_t qbase = ((size_t)bh * SS + s) * DQK;
#pragma unroll
  for (int i = 0; i < 2; i++) {
    *(half8_t*)(Qd + qbase + dq + i * 8)      = *(half8_t*)(&qc[i * 8]);
    *(half8_t*)(Qd + qbase + DH + dq + i * 8) = *(half8_t*)(&qs[i * 8]);
  }
  // K swizzled: cos dims d -> d8 = d/8; sin dims -> d8 = 8 + d/8
  {
    size_t ktb = ((size_t)bh * 32 + stile) * 8192;  // f16 base of 16KB tile
    int fo0 = (t & 3) * 2;
    *(half8_t*)(Kd + ktb + ((size_t)(fo0    ) * 64 + sl) * 8) = *(half8_t*)(&kc[0]);
    *(half8_t*)(Kd + ktb + ((size_t)(fo0 + 1) * 64 + sl) * 8) = *(half8_t*)(&kc[8]);
    *(half8_t*)(Kd + ktb + ((size_t)(fo0 + 8) * 64 + sl) * 8) = *(half8_t*)(&ks[0]);
    *(half8_t*)(Kd + ktb + ((size_t)(fo0 + 9) * 64 + sl) * 8) = *(half8_t*)(&ks[8]);
  }
  __syncthreads();
  // V swizzled: unit (k8, dv) = V[dv][keys k8*8..+7]; 2 units/thread, coalesced
#pragma unroll
  for (int i = 0; i < 2; i++) {
    int u = t * 2 + i;
    int dv = u & 63, ku = u >> 6;    // ku 0..7
    _Float16 tmp[8];
#pragma unroll
    for (int jj = 0; jj < 8; jj++) tmp[jj] = Vl[dv * 65 + ku * 8 + jj];
    *(half8_t*)(Vtd + (((size_t)bh * 32 + stile) * 8 + ku) * 512 + dv * 8) =
        *(half8_t*)tmp;
  }
}

// R10 = R7 flash byte-identical EXCEPT the work->block map (single-variable
// experiment). Old map qt=31-(bi>>5): CU-set {bi,bi+256,bi+512,bi+768} totals
// 80-4g chunk-units (80..52, mean 66); measured 51.3us/80 = 0.64us/unit ->
// heaviest CU-set is the limiter. New bijective tier map balances every
// CU-set to exactly 66 units: (32-r)+(1+r)+(24-r)+(9+r) = 66. Predicted
// flash ~43-46us if per-CU balance binds; falsifier: stays ~51 -> limiter is
// the within-block chunk critical path. (R9's peel/32-bit/pkrtz bundle
// REVERTED: VALUBusy unchanged 52% -> VALU-count theory dead; conflicts 34x.)
__global__ __launch_bounds__(256) void flash_attn(
    const _Float16* __restrict__ Qd, const _Float16* __restrict__ Kd,
    const _Float16* __restrict__ Vtd,
    const float* __restrict__ wout, const float* __restrict__ bout,
    float* __restrict__ out)
{
  int g  = blockIdx.x >> 5;
  int bh = blockIdx.x & 31;          // XCD = bh % 8 (= blockIdx % 8)
  int r8 = g & 7, tier = g >> 3;
  int nch = (tier == 0) ? 32 - r8 : (tier == 1) ? 1 + r8
          : (tier == 2) ? 24 - r8 : 9 + r8;   // 1..32, each once per bh
  int qt = nch - 1;
  int b  = bh >> 4, hh = bh & 15;
  int q0 = qt * 64;
  int wave = threadIdx.x >> 6;
  int lane = threadIdx.x & 63;
  int lm = lane & 15, lq = lane >> 4;
  int qh = wave >> 1;
  int kh = wave & 1;

  __shared__ __align__(16) _Float16 KV[2][12288];   // per buf: K 16KB + V 8KB

  const _Float16* Kg = Kd + (size_t)bh * 32 * 8192;
  const _Float16* Vg = Vtd + (size_t)bh * 32 * 4096;

  {  // preload chunk 0 -> buf 0 (flies while Q frags load below)
#pragma unroll
    for (int i = 0; i < 4; i++)
      dma16(Kg + (size_t)(wave * 4 + i) * 512 + lane * 8, &KV[0][(wave * 4 + i) * 512]);
#pragma unroll
    for (int i = 0; i < 2; i++)
      dma16(Vg + (size_t)(wave * 2 + i) * 512 + lane * 8, &KV[0][8192 + (wave * 2 + i) * 512]);
  }

  // Q B-frags resident: B[n=q][k=c*32+lq*8+j]
  const _Float16* Qb = Qd + ((size_t)bh * SS + q0 + qh * 32) * DQK;
  half8_t aq[2][4];
#pragma unroll
  for (int qtl = 0; qtl < 2; qtl++)
#pragma unroll
    for (int c = 0; c < 4; c++)
      aq[qtl][c] = *(const half8_t*)(Qb + (qtl * 16 + lm) * DQK + c * 32 + lq * 8);

  f32x4_t o[4][2];   // [dv-tile][q-tile], element = O^T[dt*16+lq*4+r][qtl*16+lm]
  float l[2] = {0.f, 0.f};
#pragma unroll
  for (int dt = 0; dt < 4; dt++)
#pragma unroll
    for (int qtl = 0; qtl < 2; qtl++) o[dt][qtl] = (f32x4_t){0.f, 0.f, 0.f, 0.f};

  const f32x4_t cinit = (f32x4_t){-EBIAS, -EBIAS, -EBIAS, -EBIAS};

  for (int kt = 0; kt < nch; ++kt) {
    int bf = kt & 1;
    __syncthreads();   // drains DMA (vmcnt0 before barrier) + compute of kt-1
    if (kt + 1 < nch) {
      int nb = (kt + 1) & 1;
      const _Float16* gK = Kg + (size_t)(kt + 1) * 8192;
      const _Float16* gV = Vg + (size_t)(kt + 1) * 4096;
#pragma unroll
      for (int i = 0; i < 4; i++)
        dma16(gK + (size_t)(wave * 4 + i) * 512 + lane * 8, &KV[nb][(wave * 4 + i) * 512]);
#pragma unroll
      for (int i = 0; i < 2; i++)
        dma16(gV + (size_t)(wave * 2 + i) * 512 + lane * 8, &KV[nb][8192 + (wave * 2 + i) * 512]);
    }

    const _Float16* lK = &KV[bf][0];
    const _Float16* lV = &KV[bf][8192];
    int k0 = kt * 64;

    // S^T - EBIAS = K Q^T + (-EBIAS) : C-layout (key = lq*4+r, q = lm)
    f32x4_t cST[2][2];
    cST[0][0] = cST[0][1] = cST[1][0] = cST[1][1] = cinit;
    __builtin_amdgcn_s_setprio(1);
#pragma unroll
    for (int c = 0; c < 4; c++) {
      half8_t k0f = *(const half8_t*)(lK + ((size_t)(c * 4 + lq) * 64 + kh * 32 + lm) * 8);
      half8_t k1f = *(const half8_t*)(lK + ((size_t)(c * 4 + lq) * 64 + kh * 32 + 16 + lm) * 8);
      cST[0][0] = __builtin_amdgcn_mfma_f32_16x16x32_f16(k0f, aq[0][c], cST[0][0], 0, 0, 0);
      cST[0][1] = __builtin_amdgcn_mfma_f32_16x16x32_f16(k0f, aq[1][c], cST[0][1], 0, 0, 0);
      cST[1][0] = __builtin_amdgcn_mfma_f32_16x16x32_f16(k1f, aq[0][c], cST[1][0], 0, 0, 0);
      cST[1][1] = __builtin_amdgcn_mfma_f32_16x16x32_f16(k1f, aq[1][c], cST[1][1], 0, 0, 0);
    }
    __builtin_amdgcn_s_setprio(0);

    // p = 2^(s2) in-register; pack -> B-frags (B[n=q=lm][k=lq*4+i])
    bool maskit = (kt == nch - 1);
    half4_t pb[2][2];
#pragma unroll
    for (int ktl = 0; ktl < 2; ktl++)
#pragma unroll
      for (int qtl = 0; qtl < 2; qtl++) {
        float pf[4];
#pragma unroll
        for (int r = 0; r < 4; r++) {
          float sv = cST[ktl][qtl][r];
          if (maskit) {
            int key  = k0 + kh * 32 + ktl * 16 + lq * 4 + r;
            int qrow = q0 + qh * 32 + qtl * 16 + lm;
            if (key > qrow) sv = -1e30f;
          }
          pf[r] = __builtin_exp2f(sv);
          l[qtl] += pf[r];
        }
        pb[ktl][qtl] = (half4_t){(_Float16)pf[0], (_Float16)pf[1],
                                 (_Float16)pf[2], (_Float16)pf[3]};
      }

    // O^T += V^T P^T : A = V^T frag (m=dv, k=key lq*4+i), 16 MFMA 16x16x16
    __builtin_amdgcn_s_setprio(1);
#pragma unroll
    for (int dt = 0; dt < 4; dt++)
#pragma unroll
      for (int kg = 0; kg < 2; kg++) {
        half4_t vf = *(const half4_t*)(lV +
            ((size_t)(kh * 4 + kg * 2 + (lq >> 1)) * 64 + dt * 16 + lm) * 8 + (lq & 1) * 4);
        o[dt][0] = __builtin_amdgcn_mfma_f32_16x16x16f16(vf, pb[kg][0], o[dt][0], 0, 0, 0);
        o[dt][1] = __builtin_amdgcn_mfma_f32_16x16x16f16(vf, pb[kg][1], o[dt][1], 0, 0, 0);
      }
    __builtin_amdgcn_s_setprio(0);
  }

  // reduce l over lq groups (keys): all lanes end with l for q = qtl*16+lm
#pragma unroll
  for (int qtl = 0; qtl < 2; qtl++) {
    l[qtl] += __shfl_xor(l[qtl], 16);
    l[qtl] += __shfl_xor(l[qtl], 32);
  }

  // combine kh halves + normalize via LDS overlaid on the idle KV buffer
  // (last chunk used buf (nch-1)&1, so buf nch&1 is free), then epilogue.
  int sc = nch & 1;
  float* Of = (float*)&KV[sc][0];        // [row][pitch 68], 17664 B < 24576 B
  float* Lf = Of + 64 * 68;
  __syncthreads();
  if (kh == 1) {
#pragma unroll
    for (int qtl = 0; qtl < 2; qtl++) {
      int row = qh * 32 + qtl * 16 + lm;
#pragma unroll
      for (int dt = 0; dt < 4; dt++)
#pragma unroll
        for (int r = 0; r < 4; r++)
          Of[row * 68 + dt * 16 + lq * 4 + r] = o[dt][qtl][r];
      if (lq == 0) Lf[row] = l[qtl];
    }
  }
  __syncthreads();
  if (kh == 0) {
#pragma unroll
    for (int qtl = 0; qtl < 2; qtl++) {
      int row = qh * 32 + qtl * 16 + lm;
      float rl = 1.f / (l[qtl] + Lf[row]);
#pragma unroll
      for (int dt = 0; dt < 4; dt++)
#pragma unroll
        for (int r = 0; r < 4; r++) {
          int idx = row * 68 + dt * 16 + lq * 4 + r;
          Of[idx] = (o[dt][qtl][r] + Of[idx]) * rl;
        }
    }
  }
  __syncthreads();
  {
    int dcol = hh * DH + lane;
    float iw = 1.f / (1.f + fabsf(wout[dcol]));
    float bo = bout[dcol];
#pragma unroll
    for (int rr = 0; rr < 16; rr++) {
      int row = wave * 16 + rr;
      float th = Of[row * 68 + lane] * iw + bo;
      out[((size_t)b * SS + q0 + row) * DD + dcol] = fsc_sum(th);
    }
  }
}

extern "C" void kernel_launch(void* const* d_in, const int* in_sizes, int n_in,
                              void* d_out, int out_size, void* d_ws, size_t ws_size,
                              hipStream_t stream) {
  (void)in_sizes; (void)n_in; (void)out_size; (void)ws_size;
  const float* x   = (const float*)d_in[0];
  const float* wq  = (const float*)d_in[1];
  const float* bq  = (const float*)d_in[2];
  const float* phq = (const float*)d_in[3];
  const float* wk  = (const float*)d_in[4];
  const float* bk  = (const float*)d_in[5];
  const float* phk = (const float*)d_in[6];
  const float* wv  = (const float*)d_in[7];
  const float* bv  = (const float*)d_in[8];
  const float* wo  = (const float*)d_in[9];
  const float* bo  = (const float*)d_in[10];

  _Float16* Qd  = (_Float16*)d_ws;
  _Float16* Kd  = Qd + (size_t)BB * HH * SS * DQK;
  _Float16* Vtd = Kd + (size_t)BB * HH * SS * DQK;

  gen_qkv<<<BB * HH * (SS / 64), 256, 0, stream>>>(
      x, wq, bq, phq, wk, bk, phk, wv, bv, Qd, Kd, Vtd);
  flash_attn<<<32 * 32, 256, 0, stream>>>(
      Qd, Kd, Vtd, wo, bo, (float*)d_out);
}

// Round 15
// 143.053 us; speedup vs baseline: 1.0200x; 1.0200x over previous
//
#include <hip/hip_runtime.h>
#include <hip/hip_bf16.h>
#include <math.h>

#define BB 2
#define SS 2048
#define HH 16
#define DH 64
#define DQK 128
#define DD (HH*DH)
// Q folded scale = (1/sqrt(128)) * log2(e)  -> scores arrive in log2 domain
#define QS2   0.12751758f
// 8 * log2(e): fixed-max bias in log2 domain (cancels exactly in softmax)
#define EBIAS 11.5415605f

typedef _Float16 half8_t __attribute__((ext_vector_type(8)));
typedef _Float16 half4_t __attribute__((ext_vector_type(4)));
typedef float f32x4_t __attribute__((ext_vector_type(4)));
typedef float f32x4v __attribute__((ext_vector_type(4)));

// Direct hardware trig on REVOLUTIONS (v_sin_f32: D=sin(S0*2pi)).
__device__ __forceinline__ void fsincos(float th, float* sn, float* cs) {
  float rev = th * 0.15915494309189535f;
  rev -= floorf(rev);
  *sn = __builtin_amdgcn_sinf(rev);
  *cs = __builtin_amdgcn_cosf(rev);
}
// cos(th)+sin(th) = sqrt(2)*sin(th + pi/4): ONE transcendental.
__device__ __forceinline__ float fsc_sum(float th) {
  float rev = th * 0.15915494309189535f + 0.125f;
  rev -= floorf(rev);
  return 1.41421356237f * __builtin_amdgcn_sinf(rev);
}

// async global->LDS DMA, 16B/lane, LDS dest = WAVE-UNIFORM base (HW adds
// lane*16); per-lane term only on the global src.
__device__ __forceinline__ void dma16(const void* g, void* l) {
  __builtin_amdgcn_global_load_lds(
      (const __attribute__((address_space(1))) unsigned int*)g,
      (__attribute__((address_space(3))) unsigned int*)l, 16, 0, 0);
}

// Block per (bh, s-tile of 64). Emits:
//   Q  row-major [bh][s][128], scale QS2 folded (log2-domain scores)
//   K  swizzled  [bh][ktile64][d8 0..15][key 0..63] 16B units
//   V  swizzled  [bh][ktile64][k8 0..7][dv 0..63]  16B units
__global__ __launch_bounds__(256) void gen_qkv(
    const float* __restrict__ x,
    const float* __restrict__ wq, const float* __restrict__ bq,
    const float* __restrict__ phq,
    const float* __restrict__ wk, const float* __restrict__ bk,
    const float* __restrict__ phk,
    const float* __restrict__ wv, const float* __restrict__ bv,
    _Float16* __restrict__ Qd, _Float16* __restrict__ Kd, _Float16* __restrict__ Vtd)
{
  int stile = blockIdx.x & 31;
  int bh    = blockIdx.x >> 5;
  int b = bh >> 4, h = bh & 15;
  int t = threadIdx.x;
  int sl = t >> 2;                 // 0..63 (key/row within tile)
  int dq = (t & 3) << 4;           // 0,16,32,48
  int s  = stile * 64 + sl;

  __shared__ _Float16 Vl[64 * 65]; // transpose buffer, odd pitch

  const float* xr = x + (((size_t)b * SS + s) * HH + h) * DH + dq;
  float xv[16];
#pragma unroll
  for (int i = 0; i < 4; i++)
    *(f32x4v*)(&xv[i * 4]) = *(const f32x4v*)(xr + i * 4);

  int hd0 = h * DH + dq;
  float iwqv[16], vbq[16], vpq[16];
  float iwkv[16], vbk[16], vpk[16];
  float iwvv[16], vbv[16];
#pragma unroll
  for (int i = 0; i < 4; i++) {
    f32x4v w4, b4, p4;
    w4 = *(const f32x4v*)(wq + hd0 + i * 4);
    b4 = *(const f32x4v*)(bq + hd0 + i * 4);
    p4 = *(const f32x4v*)(phq + hd0 + i * 4);
#pragma unroll
    for (int j = 0; j < 4; j++) {
      iwqv[i*4+j] = __builtin_amdgcn_rcpf(1.f + fabsf(w4[j]));
      vbq[i*4+j] = b4[j]; vpq[i*4+j] = p4[j];
    }
    w4 = *(const f32x4v*)(wk + hd0 + i * 4);
    b4 = *(const f32x4v*)(bk + hd0 + i * 4);
    p4 = *(const f32x4v*)(phk + hd0 + i * 4);
#pragma unroll
    for (int j = 0; j < 4; j++) {
      iwkv[i*4+j] = __builtin_amdgcn_rcpf(1.f + fabsf(w4[j]));
      vbk[i*4+j] = b4[j]; vpk[i*4+j] = p4[j];
    }
    w4 = *(const f32x4v*)(wv + hd0 + i * 4);
    b4 = *(const f32x4v*)(bv + hd0 + i * 4);
#pragma unroll
    for (int j = 0; j < 4; j++) {
      iwvv[i*4+j] = __builtin_amdgcn_rcpf(1.f + fabsf(w4[j]));
      vbv[i*4+j] = b4[j];
    }
  }

  float tv = (float)s;
  _Float16 qc[16], qs[16], kc[16], ks[16];
#pragma unroll
  for (int i = 0; i < 16; i++) {
    int d = dq + i;
    {
      float th = xv[i] * iwqv[i] + vbq[i] + tv * vpq[i];
      float sn, cs; fsincos(th, &sn, &cs);
      qc[i] = (_Float16)(cs * QS2);
      qs[i] = (_Float16)(sn * QS2);
    }
    {
      float th = xv[i] * iwkv[i] + vbk[i] + tv * vpk[i];
      float sn, cs; fsincos(th, &sn, &cs);
      kc[i] = (_Float16)cs;
      ks[i] = (_Float16)sn;
    }
    {
      float th = xv[i] * iwvv[i] + vbv[i];
      Vl[d * 65 + sl] = (_Float16)fsc_sum(th);
    }
  }
  // Q row-major
  size_t qbase = ((size_t)bh * SS + s) * DQK;
#pragma unroll
  for (int i = 0; i < 2; i++) {
    *(half8_t*)(Qd + qbase + dq + i * 8)      = *(half8_t*)(&qc[i * 8]);
    *(half8_t*)(Qd + qbase + DH + dq + i * 8) = *(half8_t*)(&qs[i * 8]);
  }
  // K swizzled: cos dims d -> d8 = d/8; sin dims -> d8 = 8 + d/8
  {
    size_t ktb = ((size_t)bh * 32 + stile) * 8192;  // f16 base of 16KB tile
    int fo0 = (t & 3) * 2;
    *(half8_t*)(Kd + ktb + ((size_t)(fo0    ) * 64 + sl) * 8) = *(half8_t*)(&kc[0]);
    *(half8_t*)(Kd + ktb + ((size_t)(fo0 + 1) * 64 + sl) * 8) = *(half8_t*)(&kc[8]);
    *(half8_t*)(Kd + ktb + ((size_t)(fo0 + 8) * 64 + sl) * 8) = *(half8_t*)(&ks[0]);
    *(half8_t*)(Kd + ktb + ((size_t)(fo0 + 9) * 64 + sl) * 8) = *(half8_t*)(&ks[8]);
  }
  __syncthreads();
  // V swizzled: unit (k8, dv) = V[dv][keys k8*8..+7]; 2 units/thread, coalesced
#pragma unroll
  for (int i = 0; i < 2; i++) {
    int u = t * 2 + i;
    int dv = u & 63, ku = u >> 6;    // ku 0..7
    _Float16 tmp[8];
#pragma unroll
    for (int jj = 0; jj < 8; jj++) tmp[jj] = Vl[dv * 65 + ku * 8 + jj];
    *(half8_t*)(Vtd + (((size_t)bh * 32 + stile) * 8 + ku) * 512 + dv * 8) =
        *(half8_t*)tmp;
  }
}

// R15 = R7 proven 4-wave structure + T14 async V (issue-early/consume-late).
// 8-wave line CLOSED (R12-R14: two decompositions failed on HW, cause not
// findable from source; all 4-wave variants pass). R3 proved V-global
// address math correct but issued V loads BETWEEN QK and PV (latency
// exposed) with a forced VGPR-64 squeeze -> regressed. Here: V loads for
// chunk kt issue right after the barrier, BEFORE the K-DMA for kt+1 --
// vmcnt FIFO order means PV's auto-wait retires the V loads while leaving
// the K prefetch in flight; QK (~80cy) + softmax (~150cy) hide V's L2
// latency (~200cy). V leaves LDS: 32KB K-only double-buffer -> 4 blocks/CU
// (16 waves, +33% vs R7's 12). No launch_bounds min-wave (R7 lesson).
__global__ __launch_bounds__(256) void flash_attn(
    const _Float16* __restrict__ Qd, const _Float16* __restrict__ Kd,
    const _Float16* __restrict__ Vtd,
    const float* __restrict__ wout, const float* __restrict__ bout,
    float* __restrict__ out)
{
  int qt = 31 - (blockIdx.x >> 5);   // LPT: heaviest first (R7 map, proven)
  int bh = blockIdx.x & 31;          // XCD = bh % 8
  int b  = bh >> 4, hh = bh & 15;
  int nch = qt + 1;
  int q0 = qt * 64;
  int wave = threadIdx.x >> 6;
  int lane = threadIdx.x & 63;
  int lm = lane & 15, lq = lane >> 4;
  int qh = wave >> 1;
  int kh = wave & 1;

  __shared__ __align__(16) _Float16 KV[2][8192];   // K only: 16KB per buf

  const _Float16* Kg = Kd + (size_t)bh * 32 * 8192;
  const _Float16* Vg = Vtd + (size_t)bh * 32 * 4096;

  {  // preload K chunk 0 -> buf 0 (flies while Q frags load below)
#pragma unroll
    for (int i = 0; i < 4; i++)
      dma16(Kg + (size_t)(wave * 4 + i) * 512 + lane * 8, &KV[0][(wave * 4 + i) * 512]);
  }

  // Q B-frags resident: B[n=q][k=c*32+lq*8+j]
  const _Float16* Qb = Qd + ((size_t)bh * SS + q0 + qh * 32) * DQK;
  half8_t aq[2][4];
#pragma unroll
  for (int qtl = 0; qtl < 2; qtl++)
#pragma unroll
    for (int c = 0; c < 4; c++)
      aq[qtl][c] = *(const half8_t*)(Qb + (qtl * 16 + lm) * DQK + c * 32 + lq * 8);

  f32x4_t o[4][2];   // [dv-tile][q-tile], element = O^T[dt*16+lq*4+r][qtl*16+lm]
  float l[2] = {0.f, 0.f};
#pragma unroll
  for (int dt = 0; dt < 4; dt++)
#pragma unroll
    for (int qtl = 0; qtl < 2; qtl++) o[dt][qtl] = (f32x4_t){0.f, 0.f, 0.f, 0.f};

  const f32x4_t cinit = (f32x4_t){-EBIAS, -EBIAS, -EBIAS, -EBIAS};

  // per-wave V fragment base (global; layout math proven in R3)
  const _Float16* vbase = Vg + ((size_t)(kh * 4 + (lq >> 1)) * 64 + lm) * 8 + (lq & 1) * 4;

  for (int kt = 0; kt < nch; ++kt) {
    int bf = kt & 1;
    __syncthreads();   // drains K-DMA of kt (vmcnt0 before barrier) + compute kt-1

    // T14: issue V loads for THIS chunk first (older in vmcnt FIFO than the
    // K prefetch below) -- PV's wait retires these, leaves the DMA in flight.
    const _Float16* gV = vbase + (size_t)kt * 4096;
    half4_t vfr[4][2];
#pragma unroll
    for (int dt = 0; dt < 4; dt++)
#pragma unroll
      for (int kg = 0; kg < 2; kg++)
        vfr[dt][kg] = *(const half4_t*)(gV + kg * 1024 + dt * 128);

    if (kt + 1 < nch) {
      int nb = (kt + 1) & 1;
      const _Float16* gK = Kg + (size_t)(kt + 1) * 8192;
#pragma unroll
      for (int i = 0; i < 4; i++)
        dma16(gK + (size_t)(wave * 4 + i) * 512 + lane * 8, &KV[nb][(wave * 4 + i) * 512]);
    }

    const _Float16* lK = &KV[bf][0];
    int k0 = kt * 64;

    // S^T - EBIAS = K Q^T + (-EBIAS) : C-layout (key = lq*4+r, q = lm)
    f32x4_t cST[2][2];
    cST[0][0] = cST[0][1] = cST[1][0] = cST[1][1] = cinit;
    __builtin_amdgcn_s_setprio(1);
#pragma unroll
    for (int c = 0; c < 4; c++) {
      half8_t k0f = *(const half8_t*)(lK + ((size_t)(c * 4 + lq) * 64 + kh * 32 + lm) * 8);
      half8_t k1f = *(const half8_t*)(lK + ((size_t)(c * 4 + lq) * 64 + kh * 32 + 16 + lm) * 8);
      cST[0][0] = __builtin_amdgcn_mfma_f32_16x16x32_f16(k0f, aq[0][c], cST[0][0], 0, 0, 0);
      cST[0][1] = __builtin_amdgcn_mfma_f32_16x16x32_f16(k0f, aq[1][c], cST[0][1], 0, 0, 0);
      cST[1][0] = __builtin_amdgcn_mfma_f32_16x16x32_f16(k1f, aq[0][c], cST[1][0], 0, 0, 0);
      cST[1][1] = __builtin_amdgcn_mfma_f32_16x16x32_f16(k1f, aq[1][c], cST[1][1], 0, 0, 0);
    }
    __builtin_amdgcn_s_setprio(0);

    // p = 2^(s2) in-register; pack -> B-frags (B[n=q=lm][k=lq*4+i])
    bool maskit = (kt == nch - 1);
    half4_t pb[2][2];
#pragma unroll
    for (int ktl = 0; ktl < 2; ktl++)
#pragma unroll
      for (int qtl = 0; qtl < 2; qtl++) {
        float pf[4];
#pragma unroll
        for (int r = 0; r < 4; r++) {
          float sv = cST[ktl][qtl][r];
          if (maskit) {
            int key  = k0 + kh * 32 + ktl * 16 + lq * 4 + r;
            int qrow = q0 + qh * 32 + qtl * 16 + lm;
            if (key > qrow) sv = -1e30f;
          }
          pf[r] = __builtin_exp2f(sv);
          l[qtl] += pf[r];
        }
        pb[ktl][qtl] = (half4_t){(_Float16)pf[0], (_Float16)pf[1],
                                 (_Float16)pf[2], (_Float16)pf[3]};
      }

    // O^T += V^T P^T : A = V^T frag (m=dv, k=key lq*4+i), 16 MFMA 16x16x16
    __builtin_amdgcn_s_setprio(1);
#pragma unroll
    for (int dt = 0; dt < 4; dt++)
#pragma unroll
      for (int kg = 0; kg < 2; kg++) {
        o[dt][0] = __builtin_amdgcn_mfma_f32_16x16x16f16(vfr[dt][kg], pb[kg][0], o[dt][0], 0, 0, 0);
        o[dt][1] = __builtin_amdgcn_mfma_f32_16x16x16f16(vfr[dt][kg], pb[kg][1], o[dt][1], 0, 0, 0);
      }
    __builtin_amdgcn_s_setprio(0);
  }

  // reduce l over lq groups (keys): all lanes end with l for q = qtl*16+lm
#pragma unroll
  for (int qtl = 0; qtl < 2; qtl++) {
    l[qtl] += __shfl_xor(l[qtl], 16);
    l[qtl] += __shfl_xor(l[qtl], 32);
  }

  // combine kh halves + normalize via LDS overlay on the K buffers (all DMA
  // drained: no prefetch issued on the last chunk). Of[row][pitch 68]:
  // 64*68*4 + 64*4 = 17664 B < 32768 B.
  float* Of = (float*)&KV[0][0];
  float* Lf = Of + 64 * 68;
  __syncthreads();
  if (kh == 1) {
#pragma unroll
    for (int qtl = 0; qtl < 2; qtl++) {
      int row = qh * 32 + qtl * 16 + lm;
#pragma unroll
      for (int dt = 0; dt < 4; dt++)
#pragma unroll
        for (int r = 0; r < 4; r++)
          Of[row * 68 + dt * 16 + lq * 4 + r] = o[dt][qtl][r];
      if (lq == 0) Lf[row] = l[qtl];
    }
  }
  __syncthreads();
  if (kh == 0) {
#pragma unroll
    for (int qtl = 0; qtl < 2; qtl++) {
      int row = qh * 32 + qtl * 16 + lm;
      float rl = 1.f / (l[qtl] + Lf[row]);
#pragma unroll
      for (int dt = 0; dt < 4; dt++)
#pragma unroll
        for (int r = 0; r < 4; r++) {
          int idx = row * 68 + dt * 16 + lq * 4 + r;
          Of[idx] = (o[dt][qtl][r] + Of[idx]) * rl;
        }
    }
  }
  __syncthreads();
  {
    int dcol = hh * DH + lane;
    float iw = 1.f / (1.f + fabsf(wout[dcol]));
    float bo = bout[dcol];
#pragma unroll
    for (int rr = 0; rr < 16; rr++) {
      int row = wave * 16 + rr;
      float th = Of[row * 68 + lane] * iw + bo;
      out[((size_t)b * SS + q0 + row) * DD + dcol] = fsc_sum(th);
    }
  }
}

extern "C" void kernel_launch(void* const* d_in, const int* in_sizes, int n_in,
                              void* d_out, int out_size, void* d_ws, size_t ws_size,
                              hipStream_t stream) {
  (void)in_sizes; (void)n_in; (void)out_size; (void)ws_size;
  const float* x   = (const float*)d_in[0];
  const float* wq  = (const float*)d_in[1];
  const float* bq  = (const float*)d_in[2];
  const float* phq = (const float*)d_in[3];
  const float* wk  = (const float*)d_in[4];
  const float* bk  = (const float*)d_in[5];
  const float* phk = (const float*)d_in[6];
  const float* wv  = (const float*)d_in[7];
  const float* bv  = (const float*)d_in[8];
  const float* wo  = (const float*)d_in[9];
  const float* bo  = (const float*)d_in[10];

  _Float16* Qd  = (_Float16*)d_ws;
  _Float16* Kd  = Qd + (size_t)BB * HH * SS * DQK;
  _Float16* Vtd = Kd + (size_t)BB * HH * SS * DQK;

  gen_qkv<<<BB * HH * (SS / 64), 256, 0, stream>>>(
      x, wq, bq, phq, wk, bk, phk, wv, bv, Qd, Kd, Vtd);
  flash_attn<<<32 * 32, 256, 0, stream>>>(
      Qd, Kd, Vtd, wo, bo, (float*)d_out);
}

// Round 16
// 141.955 us; speedup vs baseline: 1.0279x; 1.0077x over previous
//
#include <hip/hip_runtime.h>
#include <hip/hip_bf16.h>
#include <math.h>

#define BB 2
#define SS 2048
#define HH 16
#define DH 64
#define DQK 128
#define DD (HH*DH)
// Q folded scale = (1/sqrt(128)) * log2(e)  -> scores arrive in log2 domain
#define QS2   0.12751758f
// 8 * log2(e): fixed-max bias in log2 domain (cancels exactly in softmax)
#define EBIAS 11.5415605f

typedef _Float16 half8_t __attribute__((ext_vector_type(8)));
typedef _Float16 half4_t __attribute__((ext_vector_type(4)));
typedef float f32x4_t __attribute__((ext_vector_type(4)));
typedef float f32x4v __attribute__((ext_vector_type(4)));

// Direct hardware trig on REVOLUTIONS (v_sin_f32: D=sin(S0*2pi)).
__device__ __forceinline__ void fsincos(float th, float* sn, float* cs) {
  float rev = th * 0.15915494309189535f;
  rev -= floorf(rev);
  *sn = __builtin_amdgcn_sinf(rev);
  *cs = __builtin_amdgcn_cosf(rev);
}
// cos(th)+sin(th) = sqrt(2)*sin(th + pi/4): ONE transcendental.
__device__ __forceinline__ float fsc_sum(float th) {
  float rev = th * 0.15915494309189535f + 0.125f;
  rev -= floorf(rev);
  return 1.41421356237f * __builtin_amdgcn_sinf(rev);
}

// async global->LDS DMA, 16B/lane, LDS dest = WAVE-UNIFORM base (HW adds
// lane*16); per-lane term only on the global src.
__device__ __forceinline__ void dma16(const void* g, void* l) {
  __builtin_amdgcn_global_load_lds(
      (const __attribute__((address_space(1))) unsigned int*)g,
      (__attribute__((address_space(3))) unsigned int*)l, 16, 0, 0);
}

// Block per (bh, s-tile of 64). Emits:
//   Q  row-major [bh][s][128], scale QS2 folded (log2-domain scores)
//   K  swizzled  [bh][ktile64][d8 0..15][key 0..63] 16B units
//   V  swizzled  [bh][ktile64][k8 0..7][dv 0..63]  16B units
__global__ __launch_bounds__(256) void gen_qkv(
    const float* __restrict__ x,
    const float* __restrict__ wq, const float* __restrict__ bq,
    const float* __restrict__ phq,
    const float* __restrict__ wk, const float* __restrict__ bk,
    const float* __restrict__ phk,
    const float* __restrict__ wv, const float* __restrict__ bv,
    _Float16* __restrict__ Qd, _Float16* __restrict__ Kd, _Float16* __restrict__ Vtd)
{
  int stile = blockIdx.x & 31;
  int bh    = blockIdx.x >> 5;
  int b = bh >> 4, h = bh & 15;
  int t = threadIdx.x;
  int sl = t >> 2;                 // 0..63 (key/row within tile)
  int dq = (t & 3) << 4;           // 0,16,32,48
  int s  = stile * 64 + sl;

  __shared__ _Float16 Vl[64 * 65]; // transpose buffer, odd pitch

  const float* xr = x + (((size_t)b * SS + s) * HH + h) * DH + dq;
  float xv[16];
#pragma unroll
  for (int i = 0; i < 4; i++)
    *(f32x4v*)(&xv[i * 4]) = *(const f32x4v*)(xr + i * 4);

  int hd0 = h * DH + dq;
  float iwqv[16], vbq[16], vpq[16];
  float iwkv[16], vbk[16], vpk[16];
  float iwvv[16], vbv[16];
#pragma unroll
  for (int i = 0; i < 4; i++) {
    f32x4v w4, b4, p4;
    w4 = *(const f32x4v*)(wq + hd0 + i * 4);
    b4 = *(const f32x4v*)(bq + hd0 + i * 4);
    p4 = *(const f32x4v*)(phq + hd0 + i * 4);
#pragma unroll
    for (int j = 0; j < 4; j++) {
      iwqv[i*4+j] = __builtin_amdgcn_rcpf(1.f + fabsf(w4[j]));
      vbq[i*4+j] = b4[j]; vpq[i*4+j] = p4[j];
    }
    w4 = *(const f32x4v*)(wk + hd0 + i * 4);
    b4 = *(const f32x4v*)(bk + hd0 + i * 4);
    p4 = *(const f32x4v*)(phk + hd0 + i * 4);
#pragma unroll
    for (int j = 0; j < 4; j++) {
      iwkv[i*4+j] = __builtin_amdgcn_rcpf(1.f + fabsf(w4[j]));
      vbk[i*4+j] = b4[j]; vpk[i*4+j] = p4[j];
    }
    w4 = *(const f32x4v*)(wv + hd0 + i * 4);
    b4 = *(const f32x4v*)(bv + hd0 + i * 4);
#pragma unroll
    for (int j = 0; j < 4; j++) {
      iwvv[i*4+j] = __builtin_amdgcn_rcpf(1.f + fabsf(w4[j]));
      vbv[i*4+j] = b4[j];
    }
  }

  float tv = (float)s;
  _Float16 qc[16], qs[16], kc[16], ks[16];
#pragma unroll
  for (int i = 0; i < 16; i++) {
    int d = dq + i;
    {
      float th = xv[i] * iwqv[i] + vbq[i] + tv * vpq[i];
      float sn, cs; fsincos(th, &sn, &cs);
      qc[i] = (_Float16)(cs * QS2);
      qs[i] = (_Float16)(sn * QS2);
    }
    {
      float th = xv[i] * iwkv[i] + vbk[i] + tv * vpk[i];
      float sn, cs; fsincos(th, &sn, &cs);
      kc[i] = (_Float16)cs;
      ks[i] = (_Float16)sn;
    }
    {
      float th = xv[i] * iwvv[i] + vbv[i];
      Vl[d * 65 + sl] = (_Float16)fsc_sum(th);
    }
  }
  // Q row-major
  size_t qbase = ((size_t)bh * SS + s) * DQK;
#pragma unroll
  for (int i = 0; i < 2; i++) {
    *(half8_t*)(Qd + qbase + dq + i * 8)      = *(half8_t*)(&qc[i * 8]);
    *(half8_t*)(Qd + qbase + DH + dq + i * 8) = *(half8_t*)(&qs[i * 8]);
  }
  // K swizzled: cos dims d -> d8 = d/8; sin dims -> d8 = 8 + d/8
  {
    size_t ktb = ((size_t)bh * 32 + stile) * 8192;  // f16 base of 16KB tile
    int fo0 = (t & 3) * 2;
    *(half8_t*)(Kd + ktb + ((size_t)(fo0    ) * 64 + sl) * 8) = *(half8_t*)(&kc[0]);
    *(half8_t*)(Kd + ktb + ((size_t)(fo0 + 1) * 64 + sl) * 8) = *(half8_t*)(&kc[8]);
    *(half8_t*)(Kd + ktb + ((size_t)(fo0 + 8) * 64 + sl) * 8) = *(half8_t*)(&ks[0]);
    *(half8_t*)(Kd + ktb + ((size_t)(fo0 + 9) * 64 + sl) * 8) = *(half8_t*)(&ks[8]);
  }
  __syncthreads();
  // V swizzled: unit (k8, dv) = V[dv][keys k8*8..+7]; 2 units/thread, coalesced
#pragma unroll
  for (int i = 0; i < 2; i++) {
    int u = t * 2 + i;
    int dv = u & 63, ku = u >> 6;    // ku 0..7
    _Float16 tmp[8];
#pragma unroll
    for (int jj = 0; jj < 8; jj++) tmp[jj] = Vl[dv * 65 + ku * 8 + jj];
    *(half8_t*)(Vtd + (((size_t)bh * 32 + stile) * 8 + ku) * 512 + dv * 8) =
        *(half8_t*)tmp;
  }
}

// R16 = consolidation: R7 (best total, 140.6) with two evidence-backed
// micro-reverts. (1) setprio REMOVED: R0's inner loop (no setprio) measured
// 50.8 -- best flash of the session; R7 (with setprio) 51.3; T5 is null on
// barrier-lockstep schedules (m190). (2) epilogue divides -> v_rcp_f32
// (proven passing in R3 at identical absmax). Everything else byte-identical
// to R7. Session ledger: occupancy (R3/R15), split-K (R4), counted-vmcnt
// ring (R6), VALU diet (R9), CU balance (R11), 8-wave (R12-14) all refuted
// or broken on HW; flash is issue-bound at ~75% MFMA+VALU busy, residue =
// barrier drain that every restructuring attempt made worse.
__global__ __launch_bounds__(256) void flash_attn(
    const _Float16* __restrict__ Qd, const _Float16* __restrict__ Kd,
    const _Float16* __restrict__ Vtd,
    const float* __restrict__ wout, const float* __restrict__ bout,
    float* __restrict__ out)
{
  int qt = 31 - (blockIdx.x >> 5);   // LPT: heaviest first
  int bh = blockIdx.x & 31;          // XCD = bh % 8
  int b  = bh >> 4, hh = bh & 15;
  int nch = qt + 1;
  int q0 = qt * 64;
  int wave = threadIdx.x >> 6;
  int lane = threadIdx.x & 63;
  int lm = lane & 15, lq = lane >> 4;
  int qh = wave >> 1;
  int kh = wave & 1;

  __shared__ __align__(16) _Float16 KV[2][12288];   // per buf: K 16KB + V 8KB

  const _Float16* Kg = Kd + (size_t)bh * 32 * 8192;
  const _Float16* Vg = Vtd + (size_t)bh * 32 * 4096;

  {  // preload chunk 0 -> buf 0 (flies while Q frags load below)
#pragma unroll
    for (int i = 0; i < 4; i++)
      dma16(Kg + (size_t)(wave * 4 + i) * 512 + lane * 8, &KV[0][(wave * 4 + i) * 512]);
#pragma unroll
    for (int i = 0; i < 2; i++)
      dma16(Vg + (size_t)(wave * 2 + i) * 512 + lane * 8, &KV[0][8192 + (wave * 2 + i) * 512]);
  }

  // Q B-frags resident: B[n=q][k=c*32+lq*8+j]
  const _Float16* Qb = Qd + ((size_t)bh * SS + q0 + qh * 32) * DQK;
  half8_t aq[2][4];
#pragma unroll
  for (int qtl = 0; qtl < 2; qtl++)
#pragma unroll
    for (int c = 0; c < 4; c++)
      aq[qtl][c] = *(const half8_t*)(Qb + (qtl * 16 + lm) * DQK + c * 32 + lq * 8);

  f32x4_t o[4][2];   // [dv-tile][q-tile], element = O^T[dt*16+lq*4+r][qtl*16+lm]
  float l[2] = {0.f, 0.f};
#pragma unroll
  for (int dt = 0; dt < 4; dt++)
#pragma unroll
    for (int qtl = 0; qtl < 2; qtl++) o[dt][qtl] = (f32x4_t){0.f, 0.f, 0.f, 0.f};

  const f32x4_t cinit = (f32x4_t){-EBIAS, -EBIAS, -EBIAS, -EBIAS};

  for (int kt = 0; kt < nch; ++kt) {
    int bf = kt & 1;
    __syncthreads();   // drains DMA (vmcnt0 before barrier) + compute of kt-1
    if (kt + 1 < nch) {
      int nb = (kt + 1) & 1;
      const _Float16* gK = Kg + (size_t)(kt + 1) * 8192;
      const _Float16* gV = Vg + (size_t)(kt + 1) * 4096;
#pragma unroll
      for (int i = 0; i < 4; i++)
        dma16(gK + (size_t)(wave * 4 + i) * 512 + lane * 8, &KV[nb][(wave * 4 + i) * 512]);
#pragma unroll
      for (int i = 0; i < 2; i++)
        dma16(gV + (size_t)(wave * 2 + i) * 512 + lane * 8, &KV[nb][8192 + (wave * 2 + i) * 512]);
    }

    const _Float16* lK = &KV[bf][0];
    const _Float16* lV = &KV[bf][8192];
    int k0 = kt * 64;

    // S^T - EBIAS = K Q^T + (-EBIAS) : C-layout (key = lq*4+r, q = lm)
    f32x4_t cST[2][2];
    cST[0][0] = cST[0][1] = cST[1][0] = cST[1][1] = cinit;
#pragma unroll
    for (int c = 0; c < 4; c++) {
      half8_t k0f = *(const half8_t*)(lK + ((size_t)(c * 4 + lq) * 64 + kh * 32 + lm) * 8);
      half8_t k1f = *(const half8_t*)(lK + ((size_t)(c * 4 + lq) * 64 + kh * 32 + 16 + lm) * 8);
      cST[0][0] = __builtin_amdgcn_mfma_f32_16x16x32_f16(k0f, aq[0][c], cST[0][0], 0, 0, 0);
      cST[0][1] = __builtin_amdgcn_mfma_f32_16x16x32_f16(k0f, aq[1][c], cST[0][1], 0, 0, 0);
      cST[1][0] = __builtin_amdgcn_mfma_f32_16x16x32_f16(k1f, aq[0][c], cST[1][0], 0, 0, 0);
      cST[1][1] = __builtin_amdgcn_mfma_f32_16x16x32_f16(k1f, aq[1][c], cST[1][1], 0, 0, 0);
    }

    // p = 2^(s2) in-register; pack -> B-frags (B[n=q=lm][k=lq*4+i])
    bool maskit = (kt == nch - 1);
    half4_t pb[2][2];
#pragma unroll
    for (int ktl = 0; ktl < 2; ktl++)
#pragma unroll
      for (int qtl = 0; qtl < 2; qtl++) {
        float pf[4];
#pragma unroll
        for (int r = 0; r < 4; r++) {
          float sv = cST[ktl][qtl][r];
          if (maskit) {
            int key  = k0 + kh * 32 + ktl * 16 + lq * 4 + r;
            int qrow = q0 + qh * 32 + qtl * 16 + lm;
            if (key > qrow) sv = -1e30f;
          }
          pf[r] = __builtin_exp2f(sv);
          l[qtl] += pf[r];
        }
        pb[ktl][qtl] = (half4_t){(_Float16)pf[0], (_Float16)pf[1],
                                 (_Float16)pf[2], (_Float16)pf[3]};
      }

    // O^T += V^T P^T : A = V^T frag (m=dv, k=key lq*4+i), 16 MFMA 16x16x16
#pragma unroll
    for (int dt = 0; dt < 4; dt++)
#pragma unroll
      for (int kg = 0; kg < 2; kg++) {
        half4_t vf = *(const half4_t*)(lV +
            ((size_t)(kh * 4 + kg * 2 + (lq >> 1)) * 64 + dt * 16 + lm) * 8 + (lq & 1) * 4);
        o[dt][0] = __builtin_amdgcn_mfma_f32_16x16x16f16(vf, pb[kg][0], o[dt][0], 0, 0, 0);
        o[dt][1] = __builtin_amdgcn_mfma_f32_16x16x16f16(vf, pb[kg][1], o[dt][1], 0, 0, 0);
      }
  }

  // reduce l over lq groups (keys): all lanes end with l for q = qtl*16+lm
#pragma unroll
  for (int qtl = 0; qtl < 2; qtl++) {
    l[qtl] += __shfl_xor(l[qtl], 16);
    l[qtl] += __shfl_xor(l[qtl], 32);
  }

  // combine kh halves + normalize via LDS overlaid on the idle KV buffer
  // (last chunk used buf (nch-1)&1, so buf nch&1 is free), then epilogue.
  int sc = nch & 1;
  float* Of = (float*)&KV[sc][0];        // [row][pitch 68], 17664 B < 24576 B
  float* Lf = Of + 64 * 68;
  __syncthreads();
  if (kh == 1) {
#pragma unroll
    for (int qtl = 0; qtl < 2; qtl++) {
      int row = qh * 32 + qtl * 16 + lm;
#pragma unroll
      for (int dt = 0; dt < 4; dt++)
#pragma unroll
        for (int r = 0; r < 4; r++)
          Of[row * 68 + dt * 16 + lq * 4 + r] = o[dt][qtl][r];
      if (lq == 0) Lf[row] = l[qtl];
    }
  }
  __syncthreads();
  if (kh == 0) {
#pragma unroll
    for (int qtl = 0; qtl < 2; qtl++) {
      int row = qh * 32 + qtl * 16 + lm;
      float rl = __builtin_amdgcn_rcpf(l[qtl] + Lf[row]);
#pragma unroll
      for (int dt = 0; dt < 4; dt++)
#pragma unroll
        for (int r = 0; r < 4; r++) {
          int idx = row * 68 + dt * 16 + lq * 4 + r;
          Of[idx] = (o[dt][qtl][r] + Of[idx]) * rl;
        }
    }
  }
  __syncthreads();
  {
    int dcol = hh * DH + lane;
    float iw = __builtin_amdgcn_rcpf(1.f + fabsf(wout[dcol]));
    float bo = bout[dcol];
#pragma unroll
    for (int rr = 0; rr < 16; rr++) {
      int row = wave * 16 + rr;
      float th = Of[row * 68 + lane] * iw + bo;
      out[((size_t)b * SS + q0 + row) * DD + dcol] = fsc_sum(th);
    }
  }
}

extern "C" void kernel_launch(void* const* d_in, const int* in_sizes, int n_in,
                              void* d_out, int out_size, void* d_ws, size_t ws_size,
                              hipStream_t stream) {
  (void)in_sizes; (void)n_in; (void)out_size; (void)ws_size;
  const float* x   = (const float*)d_in[0];
  const float* wq  = (const float*)d_in[1];
  const float* bq  = (const float*)d_in[2];
  const float* phq = (const float*)d_in[3];
  const float* wk  = (const float*)d_in[4];
  const float* bk  = (const float*)d_in[5];
  const float* phk = (const float*)d_in[6];
  const float* wv  = (const float*)d_in[7];
  const float* bv  = (const float*)d_in[8];
  const float* wo  = (const float*)d_in[9];
  const float* bo  = (const float*)d_in[10];

  _Float16* Qd  = (_Float16*)d_ws;
  _Float16* Kd  = Qd + (size_t)BB * HH * SS * DQK;
  _Float16* Vtd = Kd + (size_t)BB * HH * SS * DQK;

  gen_qkv<<<BB * HH * (SS / 64), 256, 0, stream>>>(
      x, wq, bq, phq, wk, bk, phk, wv, bv, Qd, Kd, Vtd);
  flash_attn<<<32 * 32, 256, 0, stream>>>(
      Qd, Kd, Vtd, wo, bo, (float*)d_out);
}